// Round 9
// baseline (469.677 us; speedup 1.0000x reference)
//
#include <hip/hip_runtime.h>
#include <math.h>

namespace {
constexpr int Bn   = 8;
constexpr int CIN  = 32;
constexpr int CI   = 16;
constexpr int Lp   = 961;     // 31*31 patches
constexpr int FIN  = 784;     // 16*49
constexpr int FOUT = 196;
constexpr int F62  = 1568;    // 32*49

constexpr int FCP  = 224;                 // fc K-pad (196 -> 7*32)
constexpr long long FCB = 961LL * FCP;    // wf/xf/W2 per-batch (shorts)
constexpr int KP   = 992;                 // L K-pad (961 -> 31*32)
constexpr long long WFTB = 196LL * KP;    // wfT per-batch (shorts)
constexpr long long AMBB = 961LL * KP;    // Am_bf16 per-batch (shorts)
constexpr long long PBTB = 1568LL * KP;   // p62bT per-batch (shorts)
constexpr long long AB   = 961LL * 961;   // S per-batch (floats)
constexpr int YLD  = 964;                 // yT leading dim (shorts)
constexpr long long YB = 1568LL * YLD;    // yT per-batch (shorts)
constexpr int CK   = 288;                 // conv K: 9 taps x 32 ci (tap-major)
}

typedef __attribute__((ext_vector_type(8))) short short8x;
typedef __attribute__((ext_vector_type(4))) float floatx4;
typedef __attribute__((ext_vector_type(4))) unsigned short ushort4x;

static __device__ __forceinline__ unsigned short f2bf(float x) {
    unsigned int u = __builtin_bit_cast(unsigned int, x);
    u += 0x7fffu + ((u >> 16) & 1u);           // RNE
    return (unsigned short)(u >> 16);
}
static __device__ __forceinline__ float bf2f(unsigned short h) {
    return __builtin_bit_cast(float, ((unsigned int)h) << 16);
}

// ---------------------------------------------------------------------------
// Merged prep: conv-GEMM B hi/lo (dual + c1, tap-major K=288) + Mw hi/lo +
// Mb + fc1_w hi/lo (TAP-MAJOR k-order: k = tap*16 + c) + wfT pad zero.
// ---------------------------------------------------------------------------
__global__ __launch_bounds__(256)
void prep_k(const float* __restrict__ g_w, const float* __restrict__ w_w,
            const float* __restrict__ c1_w,
            unsigned short* __restrict__ cwh, unsigned short* __restrict__ cwl,
            unsigned short* __restrict__ c1h, unsigned short* __restrict__ c1l,
            const float* __restrict__ mconv_w, const float* __restrict__ mfc_w,
            unsigned short* __restrict__ Mwh, unsigned short* __restrict__ Mwl,
            const float* __restrict__ mconv_b, const float* __restrict__ mfc_b,
            float* __restrict__ Mb,
            const float* __restrict__ fc1w,
            unsigned short* __restrict__ Wh, unsigned short* __restrict__ Wl,
            unsigned short* __restrict__ wfTh, unsigned short* __restrict__ wfTl)
{
    int i = blockIdx.x * 256 + threadIdx.x;
    if (i < 9216) {                             // dual conv B: [32][288]
        int n = i / CK, k = i - n * CK;
        int t = k >> 5, ci = k & 31;
        float v = (n < 16) ? g_w[n * 288 + ci * 9 + t]
                           : w_w[(n - 16) * 288 + ci * 9 + t];
        unsigned short h = f2bf(v);
        cwh[i] = h; cwl[i] = f2bf(v - bf2f(h));
    } else if (i < 13824) {                     // c1 conv B: [16][288]
        int k2 = i - 9216;
        int n = k2 / CK, k = k2 - n * CK;
        int t = k >> 5, ci = k & 31;
        float v = c1_w[n * 288 + ci * 9 + t];
        unsigned short h = f2bf(v);
        c1h[k2] = h; c1l[k2] = f2bf(v - bf2f(h));
    } else if (i < 967136) {
        int k = i - 13824;                      // 961*KP
        int n = k / KP, c = k - n * KP;
        float v = (c < 961) ? (mconv_w[n * 961 + c] + mfc_w[n * 961 + c]) : 0.0f;
        unsigned short h = f2bf(v);
        Mwh[k] = h; Mwl[k] = f2bf(v - bf2f(h));
    } else if (i < 968097) {
        int k = i - 967136;
        Mb[k] = mconv_b[k] + mfc_b[k];
    } else if (i < 1172897) {
        int k = i - 968097;                     // 256*800, tap-major k-order
        int n = k / 800, kk = k - n * 800;
        int tap = kk >> 4, c = kk & 15;
        float v = (n < 196 && tap < 49) ? fc1w[n * 784 + c * 49 + tap] : 0.0f;
        unsigned short h = f2bf(v);
        Wh[k] = h; Wl[k] = f2bf(v - bf2f(h));
    } else if (i < 1223073) {
        int k = i - 1172897;                    // 8*196*32 wfT K-pad cols
        int row = k >> 5, c = k & 31;
        long long pos = (long long)row * KP + 960 + c;
        wfTh[pos] = 0; wfTl[pos] = 0;
    }
}

// ---------------------------------------------------------------------------
// Channel-last split: fp32 plane [b][32][128][128] -> bf16 hi/lo [b][h][w][32].
// Block = (b,h); LDS transpose for full coalescing both sides.
// ---------------------------------------------------------------------------
__global__ __launch_bounds__(256)
void cls_k(const float* __restrict__ src,
           unsigned short* __restrict__ dh_, unsigned short* __restrict__ dl_)
{
    __shared__ float T[4096];                   // [ci][w]
    const int b = blockIdx.x & 7, h = blockIdx.x >> 3;
    const float* sb = src + (size_t)b * 32 * 16384 + h * 128;
    for (int i = threadIdx.x; i < 4096; i += 256) {
        int ci = i >> 7, w = i & 127;
        T[i] = sb[ci * 16384 + w];
    }
    __syncthreads();
    long long obase = ((long long)b * 16384 + (long long)h * 128) * 32;
    for (int i = threadIdx.x; i < 512; i += 256) {
        int w = i >> 2, o = i & 3;
        unsigned short hv[8], lv[8];
        #pragma unroll
        for (int e = 0; e < 8; ++e) {
            float v = T[(o * 8 + e) * 128 + w];
            unsigned short hh = f2bf(v);
            hv[e] = hh; lv[e] = f2bf(v - bf2f(hh));
        }
        *(short8x*)(dh_ + obase + w * 32 + o * 8) = *(short8x*)hv;
        *(short8x*)(dl_ + obase + w * 32 + o * 8) = *(short8x*)lv;
    }
}

// ---------------------------------------------------------------------------
// 3x3 conv, reflect-pad(1), 32ch in, implicit-GEMM split-bf16 MFMA,
// channel-last tap-major K=288. Image tile staged ONCE; 9-tap loop
// barrier-free. CLOUT: outputs written channel-last bf16 hi/lo [b][pix][16]
// (x1/x2) via LDS transpose — feeds fcmfma2's vector A-gather.
// ---------------------------------------------------------------------------
template<int NOUT, bool BIAS, bool LEAKY, bool CLOUT>
__global__ __launch_bounds__(256)
void convcl_k(const unsigned short* __restrict__ Ih,
              const unsigned short* __restrict__ Il,
              const unsigned short* __restrict__ Bh,
              const unsigned short* __restrict__ Bl,
              const float* __restrict__ b1, const float* __restrict__ b2,
              float* __restrict__ o1,
              unsigned short* __restrict__ o1h, unsigned short* __restrict__ o1l,
              unsigned short* __restrict__ o2h, unsigned short* __restrict__ o2l)
{
    __shared__ unsigned short IsH[12480];       // 3*130*32
    __shared__ unsigned short IsL[12480];

    const int tid = threadIdx.x;
    const int b   = blockIdx.x & 7;             // batch == XCD (round-robin)
    const int h   = blockIdx.x >> 3;            // 0..127

    // stage: 390 pixels x 4 octets, hi+lo, 16B chunks (coalesced)
    for (int i = tid; i < 1560; i += 256) {
        int p = i >> 2, o = i & 3;
        int dh = (p >= 260) ? 2 : (p >= 130) ? 1 : 0;
        int c  = p - dh * 130;
        int gh = h - 1 + dh; gh = (gh < 0) ? 1 : (gh > 127 ? 126 : gh);
        int gw = c - 1;      gw = (gw < 0) ? 1 : (gw > 127 ? 126 : gw);
        long long src = (((long long)b * 16384 + gh * 128 + gw) << 5) + o * 8;
        int dst = p * 32 + ((o ^ ((c >> 1) & 3)) << 3);
        *(short8x*)&IsH[dst] = *(const short8x*)(Ih + src);
        *(short8x*)&IsL[dst] = *(const short8x*)(Il + src);
    }
    __syncthreads();

    const int lane = tid & 63;
    const int wv   = tid >> 6;
    const int wm   = wv * 32;
    const int fr   = lane & 15;
    const int kq   = lane >> 4;
    constexpr int NF = NOUT / 16;

    floatx4 acc[2][NF];
    #pragma unroll
    for (int i = 0; i < 2; ++i)
        #pragma unroll
        for (int j = 0; j < NF; ++j)
            acc[i][j] = (floatx4){0.f, 0.f, 0.f, 0.f};

    #pragma unroll
    for (int t = 0; t < 9; ++t) {               // barrier-free tap loop
        const int dh = t / 3, dw = t % 3;
        short8x bh_[NF], bl_[NF];
        #pragma unroll
        for (int j = 0; j < NF; ++j) {
            int nr = j * 16 + fr;
            bh_[j] = *(const short8x*)(Bh + nr * CK + t * 32 + kq * 8);
            bl_[j] = *(const short8x*)(Bl + nr * CK + t * 32 + kq * 8);
        }
        #pragma unroll
        for (int i = 0; i < 2; ++i) {
            int col = wm + i * 16 + fr + dw;     // 0..129
            int off = (dh * 130 + col) * 32 + ((kq ^ ((col >> 1) & 3)) << 3);
            short8x ah = *(const short8x*)&IsH[off];
            short8x al = *(const short8x*)&IsL[off];
            #pragma unroll
            for (int j = 0; j < NF; ++j) {
                acc[i][j] = __builtin_amdgcn_mfma_f32_16x16x32_bf16(ah, bh_[j], acc[i][j], 0, 0, 0);
                acc[i][j] = __builtin_amdgcn_mfma_f32_16x16x32_bf16(ah, bl_[j], acc[i][j], 0, 0, 0);
                acc[i][j] = __builtin_amdgcn_mfma_f32_16x16x32_bf16(al, bh_[j], acc[i][j], 0, 0, 0);
            }
        }
    }

    if constexpr (CLOUT) {
        // LDS transpose -> channel-last split out (coalesced 16B stores)
        __syncthreads();                        // IsH/IsL reads done
        #pragma unroll
        for (int j = 0; j < NF; ++j) {
            int n = j * 16 + fr;
            float bnv = 0.0f;
            if constexpr (BIAS) bnv = (n < 16) ? b1[n] : b2[n - 16];
            #pragma unroll
            for (int i = 0; i < 2; ++i) {
                int pb = wm + i * 16 + kq * 4;
                #pragma unroll
                for (int r = 0; r < 4; ++r) {
                    float v = acc[i][j][r] + bnv;
                    if constexpr (LEAKY) v = (v >= 0.0f) ? v : 0.2f * v;
                    unsigned short hh = f2bf(v);
                    IsH[(pb + r) * 32 + n] = hh;
                    IsL[(pb + r) * 32 + n] = f2bf(v - bf2f(hh));
                }
            }
        }
        __syncthreads();
        const int p  = tid >> 1;
        const int c0 = (tid & 1) * 8;
        long long base = ((long long)b * 16384 + (long long)h * 128 + p) * 16 + c0;
        *(short8x*)(o1h + base) = *(short8x*)&IsH[p * 32 + c0];
        *(short8x*)(o1l + base) = *(short8x*)&IsL[p * 32 + c0];
        if constexpr (NOUT == 32) {
            *(short8x*)(o2h + base) = *(short8x*)&IsH[p * 32 + 16 + c0];
            *(short8x*)(o2l + base) = *(short8x*)&IsL[p * 32 + 16 + c0];
        }
    } else {
        // fp32 planar out
        #pragma unroll
        for (int j = 0; j < NF; ++j) {
            int n = j * 16 + fr;
            float bnv = 0.0f;
            if constexpr (BIAS) bnv = (n < 16) ? b1[n] : b2[n - 16];
            float* dst = o1 + (((size_t)b * NOUT + n) * 128 + h) * 128;
            #pragma unroll
            for (int i = 0; i < 2; ++i) {
                int wb = wm + i * 16 + kq * 4;
                floatx4 ov;
                #pragma unroll
                for (int r = 0; r < 4; ++r) {
                    float v = acc[i][j][r] + bnv;
                    if constexpr (LEAKY) v = (v >= 0.0f) ? v : 0.2f * v;
                    ov[r] = v;
                }
                *(floatx4*)(dst + wb) = ov;
            }
        }
    }
}

// ---------------------------------------------------------------------------
// 1x1 conv, 16ch -> 32ch, pixel-per-thread. CLSRC: source is channel-last
// bf16 hi/lo (reconstruct v = hi + lo).
// ---------------------------------------------------------------------------
template<bool CLSRC, bool BIAS, bool LEAKY, bool RESID>
__global__ __launch_bounds__(256)
void conv1x1p_k(const float* __restrict__ src,
                const unsigned short* __restrict__ srcH,
                const unsigned short* __restrict__ srcL,
                const float* __restrict__ wgt,
                const float* __restrict__ bias, const float* __restrict__ resid,
                float* __restrict__ out)
{
    int idx = blockIdx.x * 256 + threadIdx.x;   // 131072 exact (512 blocks)
    int pix = idx & 16383;
    int b   = idx >> 14;
    float s[16];
    if constexpr (CLSRC) {
        long long base = ((long long)b * 16384 + pix) * 16;
        short8x h0 = *(const short8x*)(srcH + base);
        short8x h1 = *(const short8x*)(srcH + base + 8);
        short8x l0 = *(const short8x*)(srcL + base);
        short8x l1 = *(const short8x*)(srcL + base + 8);
        #pragma unroll
        for (int ci = 0; ci < 8; ++ci) {
            s[ci]     = bf2f((unsigned short)h0[ci]) + bf2f((unsigned short)l0[ci]);
            s[ci + 8] = bf2f((unsigned short)h1[ci]) + bf2f((unsigned short)l1[ci]);
        }
    } else {
        const float* sb = src + (size_t)b * CI * 16384 + pix;
        #pragma unroll
        for (int ci = 0; ci < CI; ++ci) s[ci] = sb[ci * 16384];
    }
    size_t ob = (size_t)b * 32 * 16384 + pix;
    #pragma unroll
    for (int co = 0; co < 32; ++co) {
        const float* wrow = wgt + co * CI;
        float acc = BIAS ? bias[co] : 0.0f;
        #pragma unroll
        for (int ci = 0; ci < CI; ++ci) acc += wrow[ci] * s[ci];
        if constexpr (LEAKY) acc = (acc >= 0.0f) ? acc : 0.2f * acc;
        if constexpr (RESID) acc += resid[ob + (size_t)co * 16384];
        out[ob + (size_t)co * 16384] = acc;
    }
}

// ---------------------------------------------------------------------------
// fc GEMM via split-bf16 MFMA (3-term), 64x64 tile, prefetched.
// Vector A-gather from channel-last pre-split x1/x2 (k = tap*16 + c).
// Blocks [0,484) do xf (src x1), [484,968) wf (src x2) + wfT write.
// ---------------------------------------------------------------------------
__global__ __launch_bounds__(256)
void fcmfma2_k(const unsigned short* __restrict__ x1h,
               const unsigned short* __restrict__ x1l,
               const unsigned short* __restrict__ x2h,
               const unsigned short* __restrict__ x2l,
               const unsigned short* __restrict__ Wh,
               const unsigned short* __restrict__ Wl,
               const float* __restrict__ bias,
               unsigned short* __restrict__ Xfh, unsigned short* __restrict__ Xfl,
               unsigned short* __restrict__ Wfh, unsigned short* __restrict__ Wfl,
               unsigned short* __restrict__ DTh, unsigned short* __restrict__ DTl)
{
    __shared__ unsigned short AsH[64*32], AsL[64*32], BsH[64*32], BsL[64*32];
    const int tid = threadIdx.x;
    const bool wrt = blockIdx.x >= 484;
    const int bid = wrt ? (int)blockIdx.x - 484 : (int)blockIdx.x;
    const unsigned short* Ah = wrt ? x2h : x1h;
    const unsigned short* Al = wrt ? x2l : x1l;
    unsigned short* Dh = wrt ? Wfh : Xfh;
    unsigned short* Dl = wrt ? Wfl : Xfl;
    const int tm0 = (bid >> 2) * 64;            // 121 m-tiles
    const int tn0 = (bid & 3) * 64;             // 4 n-tiles

    const int lr = tid >> 2;
    const int lc = tid & 3;
    const int gm = tm0 + lr;
    const bool mok = gm < 7688;
    int gb16 = 0;
    if (mok) {
        int b = gm / 961, pi = gm - b * 961;
        int ih = pi / 31, iw = pi - ih * 31;
        gb16 = (b * 16384 + ih * 512 + iw * 4) * 16;
    }
    const int tapAdd = lc >> 1;                 // which tap within the k-step
    const int c0a    = (lc & 1) * 8;            // channel octet
    const int pc = ((lc ^ ((lr >> 1) & 3))) * 8;
    const unsigned short* Whr = Wh + (tn0 + lr) * 800;
    const unsigned short* Wlr = Wl + (tn0 + lr) * 800;

    const int lane = tid & 63, wv = tid >> 6;
    const int wm = (wv >> 1) * 32, wn = (wv & 1) * 32;
    const int fr = lane & 15, kq = lane >> 4;

    floatx4 acc[2][2];
    #pragma unroll
    for (int i = 0; i < 2; ++i)
        #pragma unroll
        for (int j = 0; j < 2; ++j)
            acc[i][j] = (floatx4){0.f, 0.f, 0.f, 0.f};

    const short8x zz = {0,0,0,0,0,0,0,0};
    short8x pah, pal, pwh, pwl;
    auto loadA = [&](int k0) {
        int tap = (k0 >> 4) + tapAdd;
        if (mok && tap < 49) {
            int kh = tap / 7, kw = tap - kh * 7;
            int off = gb16 + kh * 2048 + kw * 16 + c0a;
            pah = *(const short8x*)(Ah + off);
            pal = *(const short8x*)(Al + off);
        } else { pah = zz; pal = zz; }
    };
    auto loadW = [&](int k0) {
        pwh = *(const short8x*)(Whr + k0 + lc * 8);
        pwl = *(const short8x*)(Wlr + k0 + lc * 8);
    };

    loadA(0); loadW(0);
    for (int k0 = 0; k0 < 800; k0 += 32) {
        *(short8x*)&AsH[lr * 32 + pc] = pah;
        *(short8x*)&AsL[lr * 32 + pc] = pal;
        *(short8x*)&BsH[lr * 32 + pc] = pwh;
        *(short8x*)&BsL[lr * 32 + pc] = pwl;
        __syncthreads();
        if (k0 + 32 < 800) { loadA(k0 + 32); loadW(k0 + 32); }
        short8x ah[2], al[2], bh[2], bl[2];
        #pragma unroll
        for (int i = 0; i < 2; ++i) {
            int mr = wm + i * 16 + fr;
            int off = mr * 32 + ((kq ^ ((mr >> 1) & 3)) * 8);
            ah[i] = *(const short8x*)&AsH[off];
            al[i] = *(const short8x*)&AsL[off];
        }
        #pragma unroll
        for (int j = 0; j < 2; ++j) {
            int nr = wn + j * 16 + fr;
            int off = nr * 32 + ((kq ^ ((nr >> 1) & 3)) * 8);
            bh[j] = *(const short8x*)&BsH[off];
            bl[j] = *(const short8x*)&BsL[off];
        }
        #pragma unroll
        for (int i = 0; i < 2; ++i)
            #pragma unroll
            for (int j = 0; j < 2; ++j) {
                acc[i][j] = __builtin_amdgcn_mfma_f32_16x16x32_bf16(ah[i], bh[j], acc[i][j], 0, 0, 0);
                acc[i][j] = __builtin_amdgcn_mfma_f32_16x16x32_bf16(ah[i], bl[j], acc[i][j], 0, 0, 0);
                acc[i][j] = __builtin_amdgcn_mfma_f32_16x16x32_bf16(al[i], bh[j], acc[i][j], 0, 0, 0);
            }
        __syncthreads();
    }

    #pragma unroll
    for (int j = 0; j < 2; ++j) {
        int n = tn0 + wn + j * 16 + fr;
        if (n >= FCP) continue;
        float bn = (n < 196) ? bias[n] : 0.0f;
        #pragma unroll
        for (int i = 0; i < 2; ++i) {
            #pragma unroll
            for (int r = 0; r < 4; ++r) {
                int l = tm0 + wm + i * 16 + kq * 4 + r;
                if (l >= 7688) continue;
                int b = l / 961, pi = l - b * 961;
                float v = (n < 196) ? (acc[i][j][r] + bn) : 0.0f;
                unsigned short h = f2bf(v);
                unsigned short lo = f2bf(v - bf2f(h));
                long long base = (long long)b * FCB + (long long)pi * FCP + n;
                Dh[base] = h;
                Dl[base] = lo;
                if (wrt && n < 196) {
                    long long tb = (long long)b * WFTB + (long long)n * KP + pi;
                    DTh[tb] = h;
                    DTl[tb] = lo;
                }
            }
        }
    }
}

// ---------------------------------------------------------------------------
// W2 = Mw @ wf  (per batch): M=961 (Mw rows, ld KP), N=196 (wfT rows, ld KP),
// K=KP. 3-term split. Writes W2 hi/lo rows (l, f) ld FCP incl. f-pad zeros.
// (r8 split-K variant reverted: unexplained absmax growth 0.0156->0.0499.)
// ---------------------------------------------------------------------------
__global__ __launch_bounds__(256)
void w2mfma_k(const unsigned short* __restrict__ Xhi,
              const unsigned short* __restrict__ Xlo,
              const unsigned short* __restrict__ Yhi,
              const unsigned short* __restrict__ Ylo,
              unsigned short* __restrict__ W2h,
              unsigned short* __restrict__ W2l)
{
    __shared__ unsigned short XsH[4096], XsL[4096], YsH[4096], YsL[4096];
    const int b   = blockIdx.x & 7;
    const int t   = blockIdx.x >> 3;            // 16 = 8 m x 2 n
    const int tm0 = (t >> 1) * 128;
    const int tn0 = (t & 1) * 128;
    const unsigned short* Ybh = Yhi + (long long)b * WFTB;
    const unsigned short* Ybl = Ylo + (long long)b * WFTB;
    const int tid = threadIdx.x;

    const int sr  = tid >> 1;
    const int sc0 = (tid & 1) * 2;
    const bool xok = (tm0 + sr) < 961;
    const bool yok = (tn0 + sr) < 196;
    const unsigned short* Xrh = Xhi + (long long)(tm0 + sr) * KP;
    const unsigned short* Xrl = Xlo + (long long)(tm0 + sr) * KP;
    const unsigned short* Yrh = Ybh + (long long)(tn0 + sr) * KP;
    const unsigned short* Yrl = Ybl + (long long)(tn0 + sr) * KP;
    const int swz = (sr >> 1) & 3;

    const int lane = tid & 63;
    const int wv   = tid >> 6;
    const int wm   = (wv >> 1) * 64, wn = (wv & 1) * 64;
    const int fr   = lane & 15;
    const int kq   = lane >> 4;

    floatx4 acc[4][4];
    #pragma unroll
    for (int i = 0; i < 4; ++i)
        #pragma unroll
        for (int j = 0; j < 4; ++j)
            acc[i][j] = (floatx4){0.f, 0.f, 0.f, 0.f};

    const short8x zz = {0,0,0,0,0,0,0,0};
    short8x pxh[2], pxl[2], pyh[2], pyl[2];
    auto loadK = [&](int k0) {
        #pragma unroll
        for (int c = 0; c < 2; ++c) {
            int kc = sc0 + c;
            pxh[c] = xok ? *(const short8x*)(Xrh + k0 + kc * 8) : zz;
            pxl[c] = xok ? *(const short8x*)(Xrl + k0 + kc * 8) : zz;
            pyh[c] = yok ? *(const short8x*)(Yrh + k0 + kc * 8) : zz;
            pyl[c] = yok ? *(const short8x*)(Yrl + k0 + kc * 8) : zz;
        }
    };

    loadK(0);
    for (int k0 = 0; k0 < KP; k0 += 32) {
        #pragma unroll
        for (int c = 0; c < 2; ++c) {
            int pc = (sc0 + c) ^ swz;
            *(short8x*)&XsH[sr * 32 + pc * 8] = pxh[c];
            *(short8x*)&XsL[sr * 32 + pc * 8] = pxl[c];
            *(short8x*)&YsH[sr * 32 + pc * 8] = pyh[c];
            *(short8x*)&YsL[sr * 32 + pc * 8] = pyl[c];
        }
        __syncthreads();
        if (k0 + 32 < KP) loadK(k0 + 32);
        short8x bh[4], bl[4];
        #pragma unroll
        for (int j = 0; j < 4; ++j) {
            int nr = wn + j * 16 + fr;
            int off = nr * 32 + ((kq ^ ((nr >> 1) & 3)) * 8);
            bh[j] = *(const short8x*)&YsH[off];
            bl[j] = *(const short8x*)&YsL[off];
        }
        #pragma unroll
        for (int i = 0; i < 4; ++i) {
            int mr = wm + i * 16 + fr;
            int off = mr * 32 + ((kq ^ ((mr >> 1) & 3)) * 8);
            short8x ah = *(const short8x*)&XsH[off];
            short8x al = *(const short8x*)&XsL[off];
            #pragma unroll
            for (int j = 0; j < 4; ++j) {
                acc[i][j] = __builtin_amdgcn_mfma_f32_16x16x32_bf16(ah, bh[j], acc[i][j], 0, 0, 0);
                acc[i][j] = __builtin_amdgcn_mfma_f32_16x16x32_bf16(ah, bl[j], acc[i][j], 0, 0, 0);
                acc[i][j] = __builtin_amdgcn_mfma_f32_16x16x32_bf16(al, bh[j], acc[i][j], 0, 0, 0);
            }
        }
        __syncthreads();
    }

    unsigned short* Wh2 = W2h + (long long)b * FCB;
    unsigned short* Wl2 = W2l + (long long)b * FCB;
    #pragma unroll
    for (int j = 0; j < 4; ++j) {
        int f = tn0 + wn + j * 16 + fr;
        if (f >= FCP) continue;
        #pragma unroll
        for (int i = 0; i < 4; ++i) {
            int lb = tm0 + wm + i * 16 + kq * 4;
            #pragma unroll
            for (int r = 0; r < 4; ++r) {
                int l = lb + r;
                if (l >= 961) continue;
                float v = acc[i][j][r];
                unsigned short h = f2bf(v);
                long long pos = (long long)l * FCP + f;
                Wh2[pos] = h;
                Wl2[pos] = f2bf(v - bf2f(h));
            }
        }
    }
}

// ---------------------------------------------------------------------------
// Fused A+Ti+S: A = wf@xf^T, Ti = W2@xf^T + Mb[l],
// S[l][m] = A * sigmoid(Ti) * scale.
// LDS-free (working set 2.6 MB/batch <= XCD L2; r3 lesson: do NOT copy this
// pattern to kernels whose per-batch operands exceed 4 MB).
// ---------------------------------------------------------------------------
__global__ __launch_bounds__(256, 2)
void atimfma_k(const unsigned short* __restrict__ Wfh,
               const unsigned short* __restrict__ Wfl,
               const unsigned short* __restrict__ W2h,
               const unsigned short* __restrict__ W2l,
               const unsigned short* __restrict__ Xfh,
               const unsigned short* __restrict__ Xfl,
               const float* __restrict__ Mb,
               float* __restrict__ Sout)
{
    const int b   = blockIdx.x & 7;             // batch == XCD (round-robin)
    const int t   = blockIdx.x >> 3;            // 64 = 8 m x 8 n
    const int tm0 = (t >> 3) * 128;             // l
    const int tn0 = (t & 7) * 128;              // m
    const int tid = threadIdx.x;

    const int lane = tid & 63;
    const int wv   = tid >> 6;
    const int wm   = (wv >> 1) * 64, wn = (wv & 1) * 64;
    const int fr   = lane & 15;
    const int kq   = lane >> 4;

    const long long bb = (long long)b * FCB;
    const unsigned short* A1h = Wfh + bb;
    const unsigned short* A1l = Wfl + bb;
    const unsigned short* A2h = W2h + bb;
    const unsigned short* A2l = W2l + bb;
    const unsigned short* Byh = Xfh + bb;
    const unsigned short* Byl = Xfl + bb;

    int aoff[4], boff[4];
    #pragma unroll
    for (int i = 0; i < 4; ++i) {
        int r = tm0 + wm + i * 16 + fr; if (r > 960) r = 960;
        aoff[i] = r * FCP + kq * 8;
    }
    #pragma unroll
    for (int j = 0; j < 4; ++j) {
        int r = tn0 + wn + j * 16 + fr; if (r > 960) r = 960;
        boff[j] = r * FCP + kq * 8;
    }

    floatx4 accA[4][4], accT[4][4];
    #pragma unroll
    for (int i = 0; i < 4; ++i)
        #pragma unroll
        for (int j = 0; j < 4; ++j) {
            accA[i][j] = (floatx4){0.f, 0.f, 0.f, 0.f};
            accT[i][j] = (floatx4){0.f, 0.f, 0.f, 0.f};
        }

    short8x f1h[2][4], f1l[2][4], f2h[2][4], f2l[2][4], fbh[2][4], fbl[2][4];

    #pragma unroll
    for (int j = 0; j < 4; ++j) {
        fbh[0][j] = *(const short8x*)(Byh + boff[j]);
        fbl[0][j] = *(const short8x*)(Byl + boff[j]);
    }
    #pragma unroll
    for (int i = 0; i < 4; ++i) {
        f1h[0][i] = *(const short8x*)(A1h + aoff[i]);
        f1l[0][i] = *(const short8x*)(A1l + aoff[i]);
        f2h[0][i] = *(const short8x*)(A2h + aoff[i]);
        f2l[0][i] = *(const short8x*)(A2l + aoff[i]);
    }

    #pragma unroll
    for (int ks = 0; ks < 7; ++ks) {            // FCP/32 = 7 K-steps
        const int cur = ks & 1, nxt = cur ^ 1;
        if (ks < 6) {
            const int k0 = (ks + 1) * 32;
            #pragma unroll
            for (int j = 0; j < 4; ++j) {
                fbh[nxt][j] = *(const short8x*)(Byh + boff[j] + k0);
                fbl[nxt][j] = *(const short8x*)(Byl + boff[j] + k0);
            }
            #pragma unroll
            for (int i = 0; i < 4; ++i) {
                f1h[nxt][i] = *(const short8x*)(A1h + aoff[i] + k0);
                f1l[nxt][i] = *(const short8x*)(A1l + aoff[i] + k0);
                f2h[nxt][i] = *(const short8x*)(A2h + aoff[i] + k0);
                f2l[nxt][i] = *(const short8x*)(A2l + aoff[i] + k0);
            }
        }
        #pragma unroll
        for (int i = 0; i < 4; ++i) {
            #pragma unroll
            for (int j = 0; j < 4; ++j) {
                accA[i][j] = __builtin_amdgcn_mfma_f32_16x16x32_bf16(f1h[cur][i], fbh[cur][j], accA[i][j], 0, 0, 0);
                accA[i][j] = __builtin_amdgcn_mfma_f32_16x16x32_bf16(f1h[cur][i], fbl[cur][j], accA[i][j], 0, 0, 0);
                accA[i][j] = __builtin_amdgcn_mfma_f32_16x16x32_bf16(f1l[cur][i], fbh[cur][j], accA[i][j], 0, 0, 0);
                accT[i][j] = __builtin_amdgcn_mfma_f32_16x16x32_bf16(f2h[cur][i], fbh[cur][j], accT[i][j], 0, 0, 0);
                accT[i][j] = __builtin_amdgcn_mfma_f32_16x16x32_bf16(f2h[cur][i], fbl[cur][j], accT[i][j], 0, 0, 0);
                accT[i][j] = __builtin_amdgcn_mfma_f32_16x16x32_bf16(f2l[cur][i], fbh[cur][j], accT[i][j], 0, 0, 0);
            }
        }
    }

    const float scale = 0.07142857142857142f;   // 196^-0.5
    float* Sb = Sout + (long long)b * AB;
    #pragma unroll
    for (int j = 0; j < 4; ++j) {
        int m = tn0 + wn + j * 16 + fr;
        if (m >= 961) continue;
        #pragma unroll
        for (int i = 0; i < 4; ++i) {
            int lb = tm0 + wm + i * 16 + kq * 4;
            #pragma unroll
            for (int r = 0; r < 4; ++r) {
                int l = lb + r;
                if (l >= 961) continue;
                float ti = accT[i][j][r] + Mb[l];
                float mask = 1.0f / (1.0f + expf(-ti));
                Sb[(long long)l * 961 + m] = accA[i][j][r] * mask * scale;
            }
        }
    }
}

// ---------------------------------------------------------------------------
// MERGED: softmax over S rows (blocks [0,7688)) + p62^T gather (blocks
// [7688,13765)). Independent reads (S vs x3) and writes (Am/Amb vs p62bT
// in the dead wfT/W2 region) — overlapping them fills the machine.
// ---------------------------------------------------------------------------
__global__ __launch_bounds__(256)
void smp62_k(const float* __restrict__ S, float* __restrict__ Am,
             unsigned short* __restrict__ Amb,
             const float* __restrict__ x3, unsigned short* __restrict__ pout)
{
    if (blockIdx.x < 7688) {
        int row = blockIdx.x;                // b*961 + l
        const float* srow = S + (long long)row * Lp;
        float*       orow = Am + (long long)row * Lp;
        unsigned short* brow = Amb + (long long)row * KP;
        int tid = threadIdx.x;

        float s[4], mb[4];
        float lmax = -INFINITY;
        #pragma unroll
        for (int j = 0; j < 4; ++j) {
            int m = tid + j * 256;
            if (m < Lp) {
                float v = srow[m];
                s[j]  = v;
                mb[j] = (v != 0.0f) ? 1.0f : 0.0f;
                lmax  = fmaxf(lmax, v);
            } else { s[j] = -INFINITY; mb[j] = 0.0f; }
        }
        __shared__ float red[256];
        red[tid] = lmax; __syncthreads();
        #pragma unroll
        for (int off = 128; off > 0; off >>= 1) {
            if (tid < off) red[tid] = fmaxf(red[tid], red[tid + off]);
            __syncthreads();
        }
        float rmax = red[0];
        __syncthreads();

        float e[4];
        float lsum = 0.0f;
        #pragma unroll
        for (int j = 0; j < 4; ++j) {
            int m = tid + j * 256;
            e[j] = (m < Lp) ? expf(s[j] - rmax) : 0.0f;
            lsum += e[j];
        }
        red[tid] = lsum; __syncthreads();
        #pragma unroll
        for (int off = 128; off > 0; off >>= 1) {
            if (tid < off) red[tid] += red[tid + off];
            __syncthreads();
        }
        float inv = 1.0f / red[0];
        #pragma unroll
        for (int j = 0; j < 4; ++j) {
            int m = tid + j * 256;
            if (m < Lp) {
                float v = e[j] * inv * mb[j];
                orow[m] = v;
                brow[m] = f2bf(v);
            } else if (m < KP) {
                brow[m] = 0;
            }
        }
    } else {
        int idx = ((int)blockIdx.x - 7688) * 256 + threadIdx.x;  // 8*1568*124
        if (idx >= 8 * 1568 * 124) return;
        int ck = idx % 124;
        int t  = idx / 124;
        int n  = t % 1568;
        int b  = t / 1568;
        int c = n / 49, rr = n - c * 49;
        int kh = rr / 7, kw = rr - kh * 7;
        const float* src = x3 + (long long)b * 524288 + c * 16384 + kh * 128 + kw;
        int k = ck * 8;
        unsigned short v[8];
        #pragma unroll
        for (int j = 0; j < 8; ++j) {
            int kk = k + j;
            if (kk < Lp) {
                int ih = kk / 31, iw = kk - ih * 31;
                v[j] = f2bf(src[ih * 512 + iw * 4]);
            } else v[j] = 0;
        }
        *(short8x*)(pout + ((long long)b * 1568 + n) * KP + k) = *(short8x*)v;
    }
}

// ---------------------------------------------------------------------------
// y = Am @ p62 via bf16 MFMA, prefetched, writes yT bf16 [b][n][l] (ld YLD).
// r2 structure (measured best: 59 us): single LDS buffer, 2 barriers/K-step.
// r3 (LDS-free) and r4 (dbuf 1-barrier) both regressed — L2/L3-supply bound.
// ---------------------------------------------------------------------------
__global__ __launch_bounds__(256)
void ymfma_k(const unsigned short* __restrict__ Amb,
             const unsigned short* __restrict__ Pbt,
             unsigned short* __restrict__ yT)
{
    __shared__ unsigned short As[128 * 32];
    __shared__ unsigned short Bs[128 * 32];
    const int b   = blockIdx.x & 7;
    const int t   = blockIdx.x >> 3;            // 104 = 13 n x 8 m
    const int tn0 = (t % 13) * 128;
    const int tm0 = (t / 13) * 128;
    const unsigned short* Ab = Amb + (long long)b * AMBB;
    const unsigned short* Bb = Pbt + (long long)b * PBTB;
    const int tid = threadIdx.x;

    const int sr  = tid >> 1;
    const int sc0 = (tid & 1) * 2;
    const bool aok = (tm0 + sr) < Lp;
    const bool bok = (tn0 + sr) < F62;
    const unsigned short* Arow = Ab + (long long)(tm0 + sr) * KP;
    const unsigned short* Brow = Bb + (long long)(tn0 + sr) * KP;
    const int swz = (sr >> 1) & 3;

    const int lane = tid & 63;
    const int wv   = tid >> 6;
    const int wm   = (wv >> 1) * 64, wn = (wv & 1) * 64;
    const int fr   = lane & 15;
    const int kq   = lane >> 4;

    floatx4 acc[4][4];
    #pragma unroll
    for (int i = 0; i < 4; ++i)
        #pragma unroll
        for (int j = 0; j < 4; ++j)
            acc[i][j] = (floatx4){0.f, 0.f, 0.f, 0.f};

    const short8x zz = {0,0,0,0,0,0,0,0};
    short8x pa[2], pb[2];
    auto loadK = [&](int k0) {
        #pragma unroll
        for (int c = 0; c < 2; ++c) {
            int kc = sc0 + c;
            pa[c] = aok ? *(const short8x*)(Arow + k0 + kc * 8) : zz;
            pb[c] = bok ? *(const short8x*)(Brow + k0 + kc * 8) : zz;
        }
    };

    loadK(0);
    for (int k0 = 0; k0 < Lp; k0 += 32) {
        #pragma unroll
        for (int c = 0; c < 2; ++c) {
            int pc = (sc0 + c) ^ swz;
            *(short8x*)&As[sr * 32 + pc * 8] = pa[c];
            *(short8x*)&Bs[sr * 32 + pc * 8] = pb[c];
        }
        __syncthreads();
        if (k0 + 32 < Lp) loadK(k0 + 32);
        short8x af[4], bfr[4];
        #pragma unroll
        for (int i = 0; i < 4; ++i) {
            int mr = wm + i * 16 + fr;
            af[i] = *(const short8x*)&As[mr * 32 + ((kq ^ ((mr >> 1) & 3)) * 8)];
        }
        #pragma unroll
        for (int j = 0; j < 4; ++j) {
            int nr = wn + j * 16 + fr;
            bfr[j] = *(const short8x*)&Bs[nr * 32 + ((kq ^ ((nr >> 1) & 3)) * 8)];
        }
        #pragma unroll
        for (int i = 0; i < 4; ++i)
            #pragma unroll
            for (int j = 0; j < 4; ++j)
                acc[i][j] = __builtin_amdgcn_mfma_f32_16x16x32_bf16(
                                af[i], bfr[j], acc[i][j], 0, 0, 0);
        __syncthreads();
    }

    unsigned short* Yb = yT + (long long)b * YB;
    #pragma unroll
    for (int j = 0; j < 4; ++j) {
        int n = tn0 + wn + j * 16 + fr;
        if (n >= F62) continue;
        unsigned short* Yr = Yb + (long long)n * YLD;
        #pragma unroll
        for (int i = 0; i < 4; ++i) {
            int lb = tm0 + wm + i * 16 + kq * 4;
            if (lb >= Lp) continue;
            ushort4x hv;
            #pragma unroll
            for (int r = 0; r < 4; ++r) hv[r] = f2bf(acc[i][j][r]);
            if (lb + 3 < Lp) {
                *(ushort4x*)(Yr + lb) = hv;
            } else {
                #pragma unroll
                for (int r = 0; r < 4; ++r)
                    if (lb + r < Lp) Yr[lb + r] = hv[r];
            }
        }
    }
}

// ---------------------------------------------------------------------------
// fold gather from yT bf16 -> (B,32,128,128) image.
// ---------------------------------------------------------------------------
__global__ __launch_bounds__(256)
void foldg_k(const unsigned short* __restrict__ yT, float* __restrict__ out)
{
    int idx = blockIdx.x * 256 + threadIdx.x;   // B*32*16384 exact
    int wc = idx & 127;
    int hr = (idx >> 7) & 127;
    int c  = (idx >> 14) & 31;
    int b  = idx >> 19;
    int ih_lo = (hr >= 6) ? ((hr - 3) >> 2) : 0;
    int ih_hi = min(hr >> 2, 30);
    int iw_lo = (wc >= 6) ? ((wc - 3) >> 2) : 0;
    int iw_hi = min(wc >> 2, 30);
    const unsigned short* Yb = yT + (long long)b * YB + (long long)c * 49 * YLD;
    float acc = 0.0f;
    for (int ih = ih_lo; ih <= ih_hi; ++ih) {
        int kh = hr - 4 * ih;
        for (int iw = iw_lo; iw <= iw_hi; ++iw) {
            int kw = wc - 4 * iw;
            acc += bf2f(Yb[(kh * 7 + kw) * YLD + ih * 31 + iw]);
        }
    }
    out[idx] = acc;
}

// ---------------------------------------------------------------------------
// Launch
// ---------------------------------------------------------------------------
extern "C" void kernel_launch(void* const* d_in, const int* in_sizes, int n_in,
                              void* d_out, int out_size, void* d_ws, size_t ws_size,
                              hipStream_t stream)
{
    const float* x       = (const float*)d_in[0];
    const float* g_w     = (const float*)d_in[1];
    const float* g_b     = (const float*)d_in[2];
    const float* w_w     = (const float*)d_in[3];
    const float* w_b     = (const float*)d_in[4];
    const float* theta_w = (const float*)d_in[5];
    const float* theta_b = (const float*)d_in[6];
    const float* fc1_w   = (const float*)d_in[7];
    const float* fc1_b   = (const float*)d_in[8];
    const float* mconv_w = (const float*)d_in[9];
    const float* mconv_b = (const float*)d_in[10];
    const float* mfc_w   = (const float*)d_in[11];
    const float* mfc_b   = (const float*)d_in[12];
    const float* c1_w    = (const float*)d_in[13];
    const float* c2_w    = (const float*)d_in[14];

    float* Am_out    = (float*)d_out;
    float* final_out = Am_out + (size_t)Bn * Lp * Lp;

    // Workspace (floats), ~112 MB
    float* ws = (float*)d_ws;
    // x1/x2 slots hold the channel-last bf16 hi/lo splits (exact fit):
    unsigned short* x1clH = (unsigned short*)ws;                // 2,097,152 shorts
    unsigned short* x1clL = (unsigned short*)(ws + 1048576);
    unsigned short* x2clH = (unsigned short*)(ws + 2097152);
    unsigned short* x2clL = (unsigned short*)(ws + 3145728);
    float* x1f   = ws;                        // final conv fp32 o1 (late reuse)
    float* x3    = ws + 4194304;              // 4,194,304 (fold target)
    unsigned short* xf_hi = (unsigned short*)(ws + 8388608);    // 1,722,112 shorts
    unsigned short* xf_lo = (unsigned short*)(ws + 9249664);
    unsigned short* wf_hi = (unsigned short*)(ws + 10110720);
    unsigned short* wf_lo = (unsigned short*)(ws + 10971776);
    float* Abuf  = ws + 11832832;             // 7,388,168 fl (xcl -> S -> yT -> foldcl)
    unsigned short* wfT_hi = (unsigned short*)(ws + 19221000); // 1,555,456 shorts
    unsigned short* wfT_lo = (unsigned short*)(ws + 19998728);
    unsigned short* W2_hi  = (unsigned short*)(ws + 20776456); // 1,722,112 shorts
    unsigned short* W2_lo  = (unsigned short*)(ws + 21637512);
    unsigned short* Mw_hi = (unsigned short*)(ws + 26847496);  // 953,312 shorts
    unsigned short* Mw_lo = (unsigned short*)(ws + 27324152);
    float* Mb    = ws + 27800808;             // 1,024
    unsigned short* fc1wh = (unsigned short*)(ws + 27801832);  // 204,800 shorts
    unsigned short* fc1wl = (unsigned short*)(ws + 27904232);  // 204,800 shorts
    // conv weights: dual-B aliases the x3 region (consumed before x3 write);
    // c1-B in the old wT slot (survives to the final conv).
    unsigned short* cwh = (unsigned short*)(ws + 4194304);     // 9,216 shorts
    unsigned short* cwl = cwh + 16384;
    unsigned short* c1h = (unsigned short*)(ws + 28006632);    // 4,608 shorts
    unsigned short* c1l = c1h + 8192;
    // channel-last split x image (shares the Abuf region, stream-ordered):
    unsigned short* xclH = (unsigned short*)(ws + 11832832);   // 4,194,304 shorts
    unsigned short* xclL = (unsigned short*)(ws + 13929984);   // 4,194,304 shorts
    unsigned short* Am_bf16 = (unsigned short*)ws;   // x1/x2 slots (cl dead)
    // p62bT -> wfT/W2 region + gap (dead after atimfma); yT -> Abuf (S dead
    // after smp62) — de-aliased so softmax+p62bt run in ONE launch.
    unsigned short* p62bT = (unsigned short*)(ws + 19221000);  // 12,443,648 sh
    unsigned short* yT    = (unsigned short*)Abuf;             // 12,092,416 sh
    unsigned short* fclH  = xclH;                    // reused after foldg
    unsigned short* fclL  = xclL;

    // merged prep
    prep_k<<<4778, 256, 0, stream>>>(
        g_w, w_w, c1_w, cwh, cwl, c1h, c1l,
        mconv_w, mfc_w, Mw_hi, Mw_lo,
        mconv_b, mfc_b, Mb, fc1_w, fc1wh, fc1wl,
        wfT_hi, wfT_lo);

    // x -> channel-last bf16 hi/lo
    cls_k<<<1024, 256, 0, stream>>>(x, xclH, xclL);

    // x1, x2 = dual 3x3 convs -> channel-last split outputs (CLOUT)
    convcl_k<32, true, false, true><<<1024, 256, 0, stream>>>(
        xclH, xclL, cwh, cwl, g_b, w_b,
        nullptr, x1clH, x1clL, x2clH, x2clL);

    // x3 = conv1x1(x1) from cl split
    conv1x1p_k<true, true, false, false><<<512, 256, 0, stream>>>(
        nullptr, x1clH, x1clL, theta_w, theta_b, nullptr, x3);

    // xf (from x1cl) + wf (from x2cl, + transposed) in ONE launch, vector A
    fcmfma2_k<<<968, 256, 0, stream>>>(
        x1clH, x1clL, x2clH, x2clL, fc1wh, fc1wl, fc1_b,
        xf_hi, xf_lo, wf_hi, wf_lo, wfT_hi, wfT_lo);

    // W2 = Mw @ wf (assoc. trick: Ti = (Mw@wf)@xf^T) — r6 single-kernel form
    w2mfma_k<<<128, 256, 0, stream>>>(
        Mw_hi, Mw_lo, wfT_hi, wfT_lo, W2_hi, W2_lo);

    // Fused: A = wf@xf^T, Ti = W2@xf^T + Mb, S = A*sigmoid(Ti)*scale
    atimfma_k<<<512, 256, 0, stream>>>(
        wf_hi, wf_lo, W2_hi, W2_lo, xf_hi, xf_lo, Mb, Abuf);

    // MERGED: Am = softmax(S)*(S!=0) -> d_out + bf16  ||  p62^T gather
    smp62_k<<<13765, 256, 0, stream>>>(
        Abuf, Am_out, Am_bf16, x3, p62bT);

    // y = Am @ p62 -> yT bf16 (Abuf; S dead), r2 structure
    ymfma_k<<<832, 256, 0, stream>>>(Am_bf16, p62bT, yT);

    // fold gather yT -> x3 fp32
    foldg_k<<<16384, 256, 0, stream>>>(yT, x3);

    // fold image -> channel-last bf16 hi/lo (yT dead)
    cls_k<<<1024, 256, 0, stream>>>(x3, fclH, fclL);

    // o1 = leaky(conv3x3(refpad(fold))), fp32 out (Am_bf16 dead)
    convcl_k<16, false, true, false><<<1024, 256, 0, stream>>>(
        fclH, fclL, c1h, c1l, nullptr, nullptr,
        x1f, nullptr, nullptr, nullptr, nullptr);

    // final = x + leaky(conv1x1(o1))
    conv1x1p_k<false, false, true, true><<<512, 256, 0, stream>>>(
        x1f, nullptr, nullptr, c2_w, nullptr, x, final_out);
}

// Round 10
// 449.836 us; speedup vs baseline: 1.0441x; 1.0441x over previous
//
#include <hip/hip_runtime.h>
#include <math.h>

namespace {
constexpr int Bn   = 8;
constexpr int CIN  = 32;
constexpr int CI   = 16;
constexpr int Lp   = 961;     // 31*31 patches
constexpr int FIN  = 784;     // 16*49
constexpr int FOUT = 196;
constexpr int F62  = 1568;    // 32*49

constexpr int FCP  = 224;                 // fc K-pad (196 -> 7*32)
constexpr long long FCB = 961LL * FCP;    // wf/xf/W2 per-batch (shorts)
constexpr int KP   = 992;                 // L K-pad (961 -> 31*32)
constexpr long long WFTB = 196LL * KP;    // wfT per-batch (shorts)
constexpr long long AMBB = 961LL * KP;    // Am_bf16 per-batch (shorts)
constexpr long long PBTB = 1568LL * KP;   // p62bT per-batch (shorts)
constexpr long long AB   = 961LL * 961;   // S per-batch (floats)
constexpr int YLD  = 964;                 // yT leading dim (shorts)
constexpr long long YB = 1568LL * YLD;    // yT per-batch (shorts)
constexpr int CK   = 288;                 // conv K: 9 taps x 32 ci (tap-major)
}

typedef __attribute__((ext_vector_type(8))) short short8x;
typedef __attribute__((ext_vector_type(4))) float floatx4;
typedef __attribute__((ext_vector_type(4))) unsigned short ushort4x;

static __device__ __forceinline__ unsigned short f2bf(float x) {
    unsigned int u = __builtin_bit_cast(unsigned int, x);
    u += 0x7fffu + ((u >> 16) & 1u);           // RNE
    return (unsigned short)(u >> 16);
}
static __device__ __forceinline__ float bf2f(unsigned short h) {
    return __builtin_bit_cast(float, ((unsigned int)h) << 16);
}

// ---------------------------------------------------------------------------
// Merged prep: conv-GEMM B hi/lo (dual + c1, tap-major K=288) + Mw hi/lo +
// Mb + fc1_w hi/lo (TAP-MAJOR k-order: k = tap*16 + c) + wfT pad zero.
// ---------------------------------------------------------------------------
__global__ __launch_bounds__(256)
void prep_k(const float* __restrict__ g_w, const float* __restrict__ w_w,
            const float* __restrict__ c1_w,
            unsigned short* __restrict__ cwh, unsigned short* __restrict__ cwl,
            unsigned short* __restrict__ c1h, unsigned short* __restrict__ c1l,
            const float* __restrict__ mconv_w, const float* __restrict__ mfc_w,
            unsigned short* __restrict__ Mwh, unsigned short* __restrict__ Mwl,
            const float* __restrict__ mconv_b, const float* __restrict__ mfc_b,
            float* __restrict__ Mb,
            const float* __restrict__ fc1w,
            unsigned short* __restrict__ Wh, unsigned short* __restrict__ Wl,
            unsigned short* __restrict__ wfTh, unsigned short* __restrict__ wfTl)
{
    int i = blockIdx.x * 256 + threadIdx.x;
    if (i < 9216) {                             // dual conv B: [32][288]
        int n = i / CK, k = i - n * CK;
        int t = k >> 5, ci = k & 31;
        float v = (n < 16) ? g_w[n * 288 + ci * 9 + t]
                           : w_w[(n - 16) * 288 + ci * 9 + t];
        unsigned short h = f2bf(v);
        cwh[i] = h; cwl[i] = f2bf(v - bf2f(h));
    } else if (i < 13824) {                     // c1 conv B: [16][288]
        int k2 = i - 9216;
        int n = k2 / CK, k = k2 - n * CK;
        int t = k >> 5, ci = k & 31;
        float v = c1_w[n * 288 + ci * 9 + t];
        unsigned short h = f2bf(v);
        c1h[k2] = h; c1l[k2] = f2bf(v - bf2f(h));
    } else if (i < 967136) {
        int k = i - 13824;                      // 961*KP
        int n = k / KP, c = k - n * KP;
        float v = (c < 961) ? (mconv_w[n * 961 + c] + mfc_w[n * 961 + c]) : 0.0f;
        unsigned short h = f2bf(v);
        Mwh[k] = h; Mwl[k] = f2bf(v - bf2f(h));
    } else if (i < 968097) {
        int k = i - 967136;
        Mb[k] = mconv_b[k] + mfc_b[k];
    } else if (i < 1172897) {
        int k = i - 968097;                     // 256*800, tap-major k-order
        int n = k / 800, kk = k - n * 800;
        int tap = kk >> 4, c = kk & 15;
        float v = (n < 196 && tap < 49) ? fc1w[n * 784 + c * 49 + tap] : 0.0f;
        unsigned short h = f2bf(v);
        Wh[k] = h; Wl[k] = f2bf(v - bf2f(h));
    } else if (i < 1223073) {
        int k = i - 1172897;                    // 8*196*32 wfT K-pad cols
        int row = k >> 5, c = k & 31;
        long long pos = (long long)row * KP + 960 + c;
        wfTh[pos] = 0; wfTl[pos] = 0;
    }
}

// ---------------------------------------------------------------------------
// Channel-last split: fp32 plane [b][32][128][128] -> bf16 hi/lo [b][h][w][32].
// Block = (b,h); LDS transpose for full coalescing both sides.
// ---------------------------------------------------------------------------
__global__ __launch_bounds__(256)
void cls_k(const float* __restrict__ src,
           unsigned short* __restrict__ dh_, unsigned short* __restrict__ dl_)
{
    __shared__ float T[4096];                   // [ci][w]
    const int b = blockIdx.x & 7, h = blockIdx.x >> 3;
    const float* sb = src + (size_t)b * 32 * 16384 + h * 128;
    for (int i = threadIdx.x; i < 4096; i += 256) {
        int ci = i >> 7, w = i & 127;
        T[i] = sb[ci * 16384 + w];
    }
    __syncthreads();
    long long obase = ((long long)b * 16384 + (long long)h * 128) * 32;
    for (int i = threadIdx.x; i < 512; i += 256) {
        int w = i >> 2, o = i & 3;
        unsigned short hv[8], lv[8];
        #pragma unroll
        for (int e = 0; e < 8; ++e) {
            float v = T[(o * 8 + e) * 128 + w];
            unsigned short hh = f2bf(v);
            hv[e] = hh; lv[e] = f2bf(v - bf2f(hh));
        }
        *(short8x*)(dh_ + obase + w * 32 + o * 8) = *(short8x*)hv;
        *(short8x*)(dl_ + obase + w * 32 + o * 8) = *(short8x*)lv;
    }
}

// ---------------------------------------------------------------------------
// FUSED fold + channel-last split: gather yT taps -> 32x128 fold tile in LDS
// (fp32) -> bf16 hi/lo [b][h][w][32]. Replaces foldg_k (67MB fp32 write) +
// cls_k (67MB read) — the fp32 round trip was lossless, so output is
// bit-identical.
// ---------------------------------------------------------------------------
__global__ __launch_bounds__(256)
void foldcl_k(const unsigned short* __restrict__ yT,
              unsigned short* __restrict__ dh_, unsigned short* __restrict__ dl_)
{
    __shared__ float T[4096];                   // [c][w]
    const int b = blockIdx.x & 7, hr = blockIdx.x >> 3;
    const int ih_lo = (hr >= 6) ? ((hr - 3) >> 2) : 0;
    const int ih_hi = min(hr >> 2, 30);
    for (int i = threadIdx.x; i < 4096; i += 256) {
        int c = i >> 7, wc = i & 127;
        int iw_lo = (wc >= 6) ? ((wc - 3) >> 2) : 0;
        int iw_hi = min(wc >> 2, 30);
        const unsigned short* Yb = yT + (long long)b * YB + (long long)c * 49 * YLD;
        float acc = 0.0f;
        for (int ih = ih_lo; ih <= ih_hi; ++ih) {
            int kh = hr - 4 * ih;
            for (int iw = iw_lo; iw <= iw_hi; ++iw) {
                int kw = wc - 4 * iw;
                acc += bf2f(Yb[(kh * 7 + kw) * YLD + ih * 31 + iw]);
            }
        }
        T[i] = acc;
    }
    __syncthreads();
    long long obase = ((long long)b * 16384 + (long long)hr * 128) * 32;
    for (int i = threadIdx.x; i < 512; i += 256) {
        int w = i >> 2, o = i & 3;
        unsigned short hv[8], lv[8];
        #pragma unroll
        for (int e = 0; e < 8; ++e) {
            float v = T[(o * 8 + e) * 128 + w];
            unsigned short hh = f2bf(v);
            hv[e] = hh; lv[e] = f2bf(v - bf2f(hh));
        }
        *(short8x*)(dh_ + obase + w * 32 + o * 8) = *(short8x*)hv;
        *(short8x*)(dl_ + obase + w * 32 + o * 8) = *(short8x*)lv;
    }
}

// ---------------------------------------------------------------------------
// 3x3 conv, reflect-pad(1), 32ch in, implicit-GEMM split-bf16 MFMA,
// channel-last tap-major K=288. Image tile staged ONCE; 9-tap loop
// barrier-free. CLOUT: outputs written channel-last bf16 hi/lo [b][pix][16]
// (x1/x2) via LDS transpose — feeds fcmfma2's vector A-gather.
// ---------------------------------------------------------------------------
template<int NOUT, bool BIAS, bool LEAKY, bool CLOUT>
__global__ __launch_bounds__(256)
void convcl_k(const unsigned short* __restrict__ Ih,
              const unsigned short* __restrict__ Il,
              const unsigned short* __restrict__ Bh,
              const unsigned short* __restrict__ Bl,
              const float* __restrict__ b1, const float* __restrict__ b2,
              float* __restrict__ o1,
              unsigned short* __restrict__ o1h, unsigned short* __restrict__ o1l,
              unsigned short* __restrict__ o2h, unsigned short* __restrict__ o2l)
{
    __shared__ unsigned short IsH[12480];       // 3*130*32
    __shared__ unsigned short IsL[12480];

    const int tid = threadIdx.x;
    const int b   = blockIdx.x & 7;             // batch == XCD (round-robin)
    const int h   = blockIdx.x >> 3;            // 0..127

    // stage: 390 pixels x 4 octets, hi+lo, 16B chunks (coalesced)
    for (int i = tid; i < 1560; i += 256) {
        int p = i >> 2, o = i & 3;
        int dh = (p >= 260) ? 2 : (p >= 130) ? 1 : 0;
        int c  = p - dh * 130;
        int gh = h - 1 + dh; gh = (gh < 0) ? 1 : (gh > 127 ? 126 : gh);
        int gw = c - 1;      gw = (gw < 0) ? 1 : (gw > 127 ? 126 : gw);
        long long src = (((long long)b * 16384 + gh * 128 + gw) << 5) + o * 8;
        int dst = p * 32 + ((o ^ ((c >> 1) & 3)) << 3);
        *(short8x*)&IsH[dst] = *(const short8x*)(Ih + src);
        *(short8x*)&IsL[dst] = *(const short8x*)(Il + src);
    }
    __syncthreads();

    const int lane = tid & 63;
    const int wv   = tid >> 6;
    const int wm   = wv * 32;
    const int fr   = lane & 15;
    const int kq   = lane >> 4;
    constexpr int NF = NOUT / 16;

    floatx4 acc[2][NF];
    #pragma unroll
    for (int i = 0; i < 2; ++i)
        #pragma unroll
        for (int j = 0; j < NF; ++j)
            acc[i][j] = (floatx4){0.f, 0.f, 0.f, 0.f};

    #pragma unroll
    for (int t = 0; t < 9; ++t) {               // barrier-free tap loop
        const int dh = t / 3, dw = t % 3;
        short8x bh_[NF], bl_[NF];
        #pragma unroll
        for (int j = 0; j < NF; ++j) {
            int nr = j * 16 + fr;
            bh_[j] = *(const short8x*)(Bh + nr * CK + t * 32 + kq * 8);
            bl_[j] = *(const short8x*)(Bl + nr * CK + t * 32 + kq * 8);
        }
        #pragma unroll
        for (int i = 0; i < 2; ++i) {
            int col = wm + i * 16 + fr + dw;     // 0..129
            int off = (dh * 130 + col) * 32 + ((kq ^ ((col >> 1) & 3)) << 3);
            short8x ah = *(const short8x*)&IsH[off];
            short8x al = *(const short8x*)&IsL[off];
            #pragma unroll
            for (int j = 0; j < NF; ++j) {
                acc[i][j] = __builtin_amdgcn_mfma_f32_16x16x32_bf16(ah, bh_[j], acc[i][j], 0, 0, 0);
                acc[i][j] = __builtin_amdgcn_mfma_f32_16x16x32_bf16(ah, bl_[j], acc[i][j], 0, 0, 0);
                acc[i][j] = __builtin_amdgcn_mfma_f32_16x16x32_bf16(al, bh_[j], acc[i][j], 0, 0, 0);
            }
        }
    }

    if constexpr (CLOUT) {
        // LDS transpose -> channel-last split out (coalesced 16B stores)
        __syncthreads();                        // IsH/IsL reads done
        #pragma unroll
        for (int j = 0; j < NF; ++j) {
            int n = j * 16 + fr;
            float bnv = 0.0f;
            if constexpr (BIAS) bnv = (n < 16) ? b1[n] : b2[n - 16];
            #pragma unroll
            for (int i = 0; i < 2; ++i) {
                int pb = wm + i * 16 + kq * 4;
                #pragma unroll
                for (int r = 0; r < 4; ++r) {
                    float v = acc[i][j][r] + bnv;
                    if constexpr (LEAKY) v = (v >= 0.0f) ? v : 0.2f * v;
                    unsigned short hh = f2bf(v);
                    IsH[(pb + r) * 32 + n] = hh;
                    IsL[(pb + r) * 32 + n] = f2bf(v - bf2f(hh));
                }
            }
        }
        __syncthreads();
        const int p  = tid >> 1;
        const int c0 = (tid & 1) * 8;
        long long base = ((long long)b * 16384 + (long long)h * 128 + p) * 16 + c0;
        *(short8x*)(o1h + base) = *(short8x*)&IsH[p * 32 + c0];
        *(short8x*)(o1l + base) = *(short8x*)&IsL[p * 32 + c0];
        if constexpr (NOUT == 32) {
            *(short8x*)(o2h + base) = *(short8x*)&IsH[p * 32 + 16 + c0];
            *(short8x*)(o2l + base) = *(short8x*)&IsL[p * 32 + 16 + c0];
        }
    } else {
        // fp32 planar out
        #pragma unroll
        for (int j = 0; j < NF; ++j) {
            int n = j * 16 + fr;
            float bnv = 0.0f;
            if constexpr (BIAS) bnv = (n < 16) ? b1[n] : b2[n - 16];
            float* dst = o1 + (((size_t)b * NOUT + n) * 128 + h) * 128;
            #pragma unroll
            for (int i = 0; i < 2; ++i) {
                int wb = wm + i * 16 + kq * 4;
                floatx4 ov;
                #pragma unroll
                for (int r = 0; r < 4; ++r) {
                    float v = acc[i][j][r] + bnv;
                    if constexpr (LEAKY) v = (v >= 0.0f) ? v : 0.2f * v;
                    ov[r] = v;
                }
                *(floatx4*)(dst + wb) = ov;
            }
        }
    }
}

// ---------------------------------------------------------------------------
// 1x1 conv, 16ch -> 32ch, pixel-per-thread. CLSRC: source is channel-last
// bf16 hi/lo (reconstruct v = hi + lo).
// ---------------------------------------------------------------------------
template<bool CLSRC, bool BIAS, bool LEAKY, bool RESID>
__global__ __launch_bounds__(256)
void conv1x1p_k(const float* __restrict__ src,
                const unsigned short* __restrict__ srcH,
                const unsigned short* __restrict__ srcL,
                const float* __restrict__ wgt,
                const float* __restrict__ bias, const float* __restrict__ resid,
                float* __restrict__ out)
{
    int idx = blockIdx.x * 256 + threadIdx.x;   // 131072 exact (512 blocks)
    int pix = idx & 16383;
    int b   = idx >> 14;
    float s[16];
    if constexpr (CLSRC) {
        long long base = ((long long)b * 16384 + pix) * 16;
        short8x h0 = *(const short8x*)(srcH + base);
        short8x h1 = *(const short8x*)(srcH + base + 8);
        short8x l0 = *(const short8x*)(srcL + base);
        short8x l1 = *(const short8x*)(srcL + base + 8);
        #pragma unroll
        for (int ci = 0; ci < 8; ++ci) {
            s[ci]     = bf2f((unsigned short)h0[ci]) + bf2f((unsigned short)l0[ci]);
            s[ci + 8] = bf2f((unsigned short)h1[ci]) + bf2f((unsigned short)l1[ci]);
        }
    } else {
        const float* sb = src + (size_t)b * CI * 16384 + pix;
        #pragma unroll
        for (int ci = 0; ci < CI; ++ci) s[ci] = sb[ci * 16384];
    }
    size_t ob = (size_t)b * 32 * 16384 + pix;
    #pragma unroll
    for (int co = 0; co < 32; ++co) {
        const float* wrow = wgt + co * CI;
        float acc = BIAS ? bias[co] : 0.0f;
        #pragma unroll
        for (int ci = 0; ci < CI; ++ci) acc += wrow[ci] * s[ci];
        if constexpr (LEAKY) acc = (acc >= 0.0f) ? acc : 0.2f * acc;
        if constexpr (RESID) acc += resid[ob + (size_t)co * 16384];
        out[ob + (size_t)co * 16384] = acc;
    }
}

// ---------------------------------------------------------------------------
// fc GEMM via split-bf16 MFMA (3-term), 64x64 tile, prefetched.
// Vector A-gather from channel-last pre-split x1/x2 (k = tap*16 + c).
// Blocks [0,484) do xf (src x1), [484,968) wf (src x2) + wfT write.
// ---------------------------------------------------------------------------
__global__ __launch_bounds__(256)
void fcmfma2_k(const unsigned short* __restrict__ x1h,
               const unsigned short* __restrict__ x1l,
               const unsigned short* __restrict__ x2h,
               const unsigned short* __restrict__ x2l,
               const unsigned short* __restrict__ Wh,
               const unsigned short* __restrict__ Wl,
               const float* __restrict__ bias,
               unsigned short* __restrict__ Xfh, unsigned short* __restrict__ Xfl,
               unsigned short* __restrict__ Wfh, unsigned short* __restrict__ Wfl,
               unsigned short* __restrict__ DTh, unsigned short* __restrict__ DTl)
{
    __shared__ unsigned short AsH[64*32], AsL[64*32], BsH[64*32], BsL[64*32];
    const int tid = threadIdx.x;
    const bool wrt = blockIdx.x >= 484;
    const int bid = wrt ? (int)blockIdx.x - 484 : (int)blockIdx.x;
    const unsigned short* Ah = wrt ? x2h : x1h;
    const unsigned short* Al = wrt ? x2l : x1l;
    unsigned short* Dh = wrt ? Wfh : Xfh;
    unsigned short* Dl = wrt ? Wfl : Xfl;
    const int tm0 = (bid >> 2) * 64;            // 121 m-tiles
    const int tn0 = (bid & 3) * 64;             // 4 n-tiles

    const int lr = tid >> 2;
    const int lc = tid & 3;
    const int gm = tm0 + lr;
    const bool mok = gm < 7688;
    int gb16 = 0;
    if (mok) {
        int b = gm / 961, pi = gm - b * 961;
        int ih = pi / 31, iw = pi - ih * 31;
        gb16 = (b * 16384 + ih * 512 + iw * 4) * 16;
    }
    const int tapAdd = lc >> 1;                 // which tap within the k-step
    const int c0a    = (lc & 1) * 8;            // channel octet
    const int pc = ((lc ^ ((lr >> 1) & 3))) * 8;
    const unsigned short* Whr = Wh + (tn0 + lr) * 800;
    const unsigned short* Wlr = Wl + (tn0 + lr) * 800;

    const int lane = tid & 63, wv = tid >> 6;
    const int wm = (wv >> 1) * 32, wn = (wv & 1) * 32;
    const int fr = lane & 15, kq = lane >> 4;

    floatx4 acc[2][2];
    #pragma unroll
    for (int i = 0; i < 2; ++i)
        #pragma unroll
        for (int j = 0; j < 2; ++j)
            acc[i][j] = (floatx4){0.f, 0.f, 0.f, 0.f};

    const short8x zz = {0,0,0,0,0,0,0,0};
    short8x pah, pal, pwh, pwl;
    auto loadA = [&](int k0) {
        int tap = (k0 >> 4) + tapAdd;
        if (mok && tap < 49) {
            int kh = tap / 7, kw = tap - kh * 7;
            int off = gb16 + kh * 2048 + kw * 16 + c0a;
            pah = *(const short8x*)(Ah + off);
            pal = *(const short8x*)(Al + off);
        } else { pah = zz; pal = zz; }
    };
    auto loadW = [&](int k0) {
        pwh = *(const short8x*)(Whr + k0 + lc * 8);
        pwl = *(const short8x*)(Wlr + k0 + lc * 8);
    };

    loadA(0); loadW(0);
    for (int k0 = 0; k0 < 800; k0 += 32) {
        *(short8x*)&AsH[lr * 32 + pc] = pah;
        *(short8x*)&AsL[lr * 32 + pc] = pal;
        *(short8x*)&BsH[lr * 32 + pc] = pwh;
        *(short8x*)&BsL[lr * 32 + pc] = pwl;
        __syncthreads();
        if (k0 + 32 < 800) { loadA(k0 + 32); loadW(k0 + 32); }
        short8x ah[2], al[2], bh[2], bl[2];
        #pragma unroll
        for (int i = 0; i < 2; ++i) {
            int mr = wm + i * 16 + fr;
            int off = mr * 32 + ((kq ^ ((mr >> 1) & 3)) * 8);
            ah[i] = *(const short8x*)&AsH[off];
            al[i] = *(const short8x*)&AsL[off];
        }
        #pragma unroll
        for (int j = 0; j < 2; ++j) {
            int nr = wn + j * 16 + fr;
            int off = nr * 32 + ((kq ^ ((nr >> 1) & 3)) * 8);
            bh[j] = *(const short8x*)&BsH[off];
            bl[j] = *(const short8x*)&BsL[off];
        }
        #pragma unroll
        for (int i = 0; i < 2; ++i)
            #pragma unroll
            for (int j = 0; j < 2; ++j) {
                acc[i][j] = __builtin_amdgcn_mfma_f32_16x16x32_bf16(ah[i], bh[j], acc[i][j], 0, 0, 0);
                acc[i][j] = __builtin_amdgcn_mfma_f32_16x16x32_bf16(ah[i], bl[j], acc[i][j], 0, 0, 0);
                acc[i][j] = __builtin_amdgcn_mfma_f32_16x16x32_bf16(al[i], bh[j], acc[i][j], 0, 0, 0);
            }
        __syncthreads();
    }

    #pragma unroll
    for (int j = 0; j < 2; ++j) {
        int n = tn0 + wn + j * 16 + fr;
        if (n >= FCP) continue;
        float bn = (n < 196) ? bias[n] : 0.0f;
        #pragma unroll
        for (int i = 0; i < 2; ++i) {
            #pragma unroll
            for (int r = 0; r < 4; ++r) {
                int l = tm0 + wm + i * 16 + kq * 4 + r;
                if (l >= 7688) continue;
                int b = l / 961, pi = l - b * 961;
                float v = (n < 196) ? (acc[i][j][r] + bn) : 0.0f;
                unsigned short h = f2bf(v);
                unsigned short lo = f2bf(v - bf2f(h));
                long long base = (long long)b * FCB + (long long)pi * FCP + n;
                Dh[base] = h;
                Dl[base] = lo;
                if (wrt && n < 196) {
                    long long tb = (long long)b * WFTB + (long long)n * KP + pi;
                    DTh[tb] = h;
                    DTl[tb] = lo;
                }
            }
        }
    }
}

// ---------------------------------------------------------------------------
// W2 = Mw @ wf  (per batch): M=961 (Mw rows, ld KP), N=196 (wfT rows, ld KP),
// K=KP. 3-term split. Writes W2 hi/lo rows (l, f) ld FCP incl. f-pad zeros.
// ---------------------------------------------------------------------------
__global__ __launch_bounds__(256)
void w2mfma_k(const unsigned short* __restrict__ Xhi,
              const unsigned short* __restrict__ Xlo,
              const unsigned short* __restrict__ Yhi,
              const unsigned short* __restrict__ Ylo,
              unsigned short* __restrict__ W2h,
              unsigned short* __restrict__ W2l)
{
    __shared__ unsigned short XsH[4096], XsL[4096], YsH[4096], YsL[4096];
    const int b   = blockIdx.x & 7;
    const int t   = blockIdx.x >> 3;            // 16 = 8 m x 2 n
    const int tm0 = (t >> 1) * 128;
    const int tn0 = (t & 1) * 128;
    const unsigned short* Ybh = Yhi + (long long)b * WFTB;
    const unsigned short* Ybl = Ylo + (long long)b * WFTB;
    const int tid = threadIdx.x;

    const int sr  = tid >> 1;
    const int sc0 = (tid & 1) * 2;
    const bool xok = (tm0 + sr) < 961;
    const bool yok = (tn0 + sr) < 196;
    const unsigned short* Xrh = Xhi + (long long)(tm0 + sr) * KP;
    const unsigned short* Xrl = Xlo + (long long)(tm0 + sr) * KP;
    const unsigned short* Yrh = Ybh + (long long)(tn0 + sr) * KP;
    const unsigned short* Yrl = Ybl + (long long)(tn0 + sr) * KP;
    const int swz = (sr >> 1) & 3;

    const int lane = tid & 63;
    const int wv   = tid >> 6;
    const int wm   = (wv >> 1) * 64, wn = (wv & 1) * 64;
    const int fr   = lane & 15;
    const int kq   = lane >> 4;

    floatx4 acc[4][4];
    #pragma unroll
    for (int i = 0; i < 4; ++i)
        #pragma unroll
        for (int j = 0; j < 4; ++j)
            acc[i][j] = (floatx4){0.f, 0.f, 0.f, 0.f};

    const short8x zz = {0,0,0,0,0,0,0,0};
    short8x pxh[2], pxl[2], pyh[2], pyl[2];
    auto loadK = [&](int k0) {
        #pragma unroll
        for (int c = 0; c < 2; ++c) {
            int kc = sc0 + c;
            pxh[c] = xok ? *(const short8x*)(Xrh + k0 + kc * 8) : zz;
            pxl[c] = xok ? *(const short8x*)(Xrl + k0 + kc * 8) : zz;
            pyh[c] = yok ? *(const short8x*)(Yrh + k0 + kc * 8) : zz;
            pyl[c] = yok ? *(const short8x*)(Yrl + k0 + kc * 8) : zz;
        }
    };

    loadK(0);
    for (int k0 = 0; k0 < KP; k0 += 32) {
        #pragma unroll
        for (int c = 0; c < 2; ++c) {
            int pc = (sc0 + c) ^ swz;
            *(short8x*)&XsH[sr * 32 + pc * 8] = pxh[c];
            *(short8x*)&XsL[sr * 32 + pc * 8] = pxl[c];
            *(short8x*)&YsH[sr * 32 + pc * 8] = pyh[c];
            *(short8x*)&YsL[sr * 32 + pc * 8] = pyl[c];
        }
        __syncthreads();
        if (k0 + 32 < KP) loadK(k0 + 32);
        short8x bh[4], bl[4];
        #pragma unroll
        for (int j = 0; j < 4; ++j) {
            int nr = wn + j * 16 + fr;
            int off = nr * 32 + ((kq ^ ((nr >> 1) & 3)) * 8);
            bh[j] = *(const short8x*)&YsH[off];
            bl[j] = *(const short8x*)&YsL[off];
        }
        #pragma unroll
        for (int i = 0; i < 4; ++i) {
            int mr = wm + i * 16 + fr;
            int off = mr * 32 + ((kq ^ ((mr >> 1) & 3)) * 8);
            short8x ah = *(const short8x*)&XsH[off];
            short8x al = *(const short8x*)&XsL[off];
            #pragma unroll
            for (int j = 0; j < 4; ++j) {
                acc[i][j] = __builtin_amdgcn_mfma_f32_16x16x32_bf16(ah, bh[j], acc[i][j], 0, 0, 0);
                acc[i][j] = __builtin_amdgcn_mfma_f32_16x16x32_bf16(ah, bl[j], acc[i][j], 0, 0, 0);
                acc[i][j] = __builtin_amdgcn_mfma_f32_16x16x32_bf16(al, bh[j], acc[i][j], 0, 0, 0);
            }
        }
        __syncthreads();
    }

    unsigned short* Wh2 = W2h + (long long)b * FCB;
    unsigned short* Wl2 = W2l + (long long)b * FCB;
    #pragma unroll
    for (int j = 0; j < 4; ++j) {
        int f = tn0 + wn + j * 16 + fr;
        if (f >= FCP) continue;
        #pragma unroll
        for (int i = 0; i < 4; ++i) {
            int lb = tm0 + wm + i * 16 + kq * 4;
            #pragma unroll
            for (int r = 0; r < 4; ++r) {
                int l = lb + r;
                if (l >= 961) continue;
                float v = acc[i][j][r];
                unsigned short h = f2bf(v);
                long long pos = (long long)l * FCP + f;
                Wh2[pos] = h;
                Wl2[pos] = f2bf(v - bf2f(h));
            }
        }
    }
}

// ---------------------------------------------------------------------------
// Fused A+Ti+S: A = wf@xf^T, Ti = W2@xf^T + Mb[l],
// S[l][m] = A * sigmoid(Ti) * scale.
// LDS-free (working set 2.6 MB/batch <= XCD L2; r3 lesson: do NOT copy this
// pattern to kernels whose per-batch operands exceed 4 MB).
// ---------------------------------------------------------------------------
__global__ __launch_bounds__(256, 2)
void atimfma_k(const unsigned short* __restrict__ Wfh,
               const unsigned short* __restrict__ Wfl,
               const unsigned short* __restrict__ W2h,
               const unsigned short* __restrict__ W2l,
               const unsigned short* __restrict__ Xfh,
               const unsigned short* __restrict__ Xfl,
               const float* __restrict__ Mb,
               float* __restrict__ Sout)
{
    const int b   = blockIdx.x & 7;             // batch == XCD (round-robin)
    const int t   = blockIdx.x >> 3;            // 64 = 8 m x 8 n
    const int tm0 = (t >> 3) * 128;             // l
    const int tn0 = (t & 7) * 128;              // m
    const int tid = threadIdx.x;

    const int lane = tid & 63;
    const int wv   = tid >> 6;
    const int wm   = (wv >> 1) * 64, wn = (wv & 1) * 64;
    const int fr   = lane & 15;
    const int kq   = lane >> 4;

    const long long bb = (long long)b * FCB;
    const unsigned short* A1h = Wfh + bb;
    const unsigned short* A1l = Wfl + bb;
    const unsigned short* A2h = W2h + bb;
    const unsigned short* A2l = W2l + bb;
    const unsigned short* Byh = Xfh + bb;
    const unsigned short* Byl = Xfl + bb;

    int aoff[4], boff[4];
    #pragma unroll
    for (int i = 0; i < 4; ++i) {
        int r = tm0 + wm + i * 16 + fr; if (r > 960) r = 960;
        aoff[i] = r * FCP + kq * 8;
    }
    #pragma unroll
    for (int j = 0; j < 4; ++j) {
        int r = tn0 + wn + j * 16 + fr; if (r > 960) r = 960;
        boff[j] = r * FCP + kq * 8;
    }

    floatx4 accA[4][4], accT[4][4];
    #pragma unroll
    for (int i = 0; i < 4; ++i)
        #pragma unroll
        for (int j = 0; j < 4; ++j) {
            accA[i][j] = (floatx4){0.f, 0.f, 0.f, 0.f};
            accT[i][j] = (floatx4){0.f, 0.f, 0.f, 0.f};
        }

    short8x f1h[2][4], f1l[2][4], f2h[2][4], f2l[2][4], fbh[2][4], fbl[2][4];

    #pragma unroll
    for (int j = 0; j < 4; ++j) {
        fbh[0][j] = *(const short8x*)(Byh + boff[j]);
        fbl[0][j] = *(const short8x*)(Byl + boff[j]);
    }
    #pragma unroll
    for (int i = 0; i < 4; ++i) {
        f1h[0][i] = *(const short8x*)(A1h + aoff[i]);
        f1l[0][i] = *(const short8x*)(A1l + aoff[i]);
        f2h[0][i] = *(const short8x*)(A2h + aoff[i]);
        f2l[0][i] = *(const short8x*)(A2l + aoff[i]);
    }

    #pragma unroll
    for (int ks = 0; ks < 7; ++ks) {            // FCP/32 = 7 K-steps
        const int cur = ks & 1, nxt = cur ^ 1;
        if (ks < 6) {
            const int k0 = (ks + 1) * 32;
            #pragma unroll
            for (int j = 0; j < 4; ++j) {
                fbh[nxt][j] = *(const short8x*)(Byh + boff[j] + k0);
                fbl[nxt][j] = *(const short8x*)(Byl + boff[j] + k0);
            }
            #pragma unroll
            for (int i = 0; i < 4; ++i) {
                f1h[nxt][i] = *(const short8x*)(A1h + aoff[i] + k0);
                f1l[nxt][i] = *(const short8x*)(A1l + aoff[i] + k0);
                f2h[nxt][i] = *(const short8x*)(A2h + aoff[i] + k0);
                f2l[nxt][i] = *(const short8x*)(A2l + aoff[i] + k0);
            }
        }
        #pragma unroll
        for (int i = 0; i < 4; ++i) {
            #pragma unroll
            for (int j = 0; j < 4; ++j) {
                accA[i][j] = __builtin_amdgcn_mfma_f32_16x16x32_bf16(f1h[cur][i], fbh[cur][j], accA[i][j], 0, 0, 0);
                accA[i][j] = __builtin_amdgcn_mfma_f32_16x16x32_bf16(f1h[cur][i], fbl[cur][j], accA[i][j], 0, 0, 0);
                accA[i][j] = __builtin_amdgcn_mfma_f32_16x16x32_bf16(f1l[cur][i], fbh[cur][j], accA[i][j], 0, 0, 0);
                accT[i][j] = __builtin_amdgcn_mfma_f32_16x16x32_bf16(f2h[cur][i], fbh[cur][j], accT[i][j], 0, 0, 0);
                accT[i][j] = __builtin_amdgcn_mfma_f32_16x16x32_bf16(f2h[cur][i], fbl[cur][j], accT[i][j], 0, 0, 0);
                accT[i][j] = __builtin_amdgcn_mfma_f32_16x16x32_bf16(f2l[cur][i], fbh[cur][j], accT[i][j], 0, 0, 0);
            }
        }
    }

    const float scale = 0.07142857142857142f;   // 196^-0.5
    float* Sb = Sout + (long long)b * AB;
    #pragma unroll
    for (int j = 0; j < 4; ++j) {
        int m = tn0 + wn + j * 16 + fr;
        if (m >= 961) continue;
        #pragma unroll
        for (int i = 0; i < 4; ++i) {
            int lb = tm0 + wm + i * 16 + kq * 4;
            #pragma unroll
            for (int r = 0; r < 4; ++r) {
                int l = lb + r;
                if (l >= 961) continue;
                float ti = accT[i][j][r] + Mb[l];
                float mask = 1.0f / (1.0f + expf(-ti));
                Sb[(long long)l * 961 + m] = accA[i][j][r] * mask * scale;
            }
        }
    }
}

// ---------------------------------------------------------------------------
// softmax over S rows (961): mb=(s!=0); Am fp32 -> d_out, bf16 (KP rows) -> ws
// ---------------------------------------------------------------------------
__global__ __launch_bounds__(256)
void softmax_mask_k(const float* __restrict__ S, float* __restrict__ Am,
                    unsigned short* __restrict__ Amb)
{
    int row = blockIdx.x;                // b*961 + l
    const float* srow = S + (long long)row * Lp;
    float*       orow = Am + (long long)row * Lp;
    unsigned short* brow = Amb + (long long)row * KP;
    int tid = threadIdx.x;

    float s[4], mb[4];
    float lmax = -INFINITY;
    #pragma unroll
    for (int j = 0; j < 4; ++j) {
        int m = tid + j * 256;
        if (m < Lp) {
            float v = srow[m];
            s[j]  = v;
            mb[j] = (v != 0.0f) ? 1.0f : 0.0f;
            lmax  = fmaxf(lmax, v);
        } else { s[j] = -INFINITY; mb[j] = 0.0f; }
    }
    __shared__ float red[256];
    red[tid] = lmax; __syncthreads();
    #pragma unroll
    for (int off = 128; off > 0; off >>= 1) {
        if (tid < off) red[tid] = fmaxf(red[tid], red[tid + off]);
        __syncthreads();
    }
    float rmax = red[0];
    __syncthreads();

    float e[4];
    float lsum = 0.0f;
    #pragma unroll
    for (int j = 0; j < 4; ++j) {
        int m = tid + j * 256;
        e[j] = (m < Lp) ? expf(s[j] - rmax) : 0.0f;
        lsum += e[j];
    }
    red[tid] = lsum; __syncthreads();
    #pragma unroll
    for (int off = 128; off > 0; off >>= 1) {
        if (tid < off) red[tid] += red[tid + off];
        __syncthreads();
    }
    float inv = 1.0f / red[0];
    #pragma unroll
    for (int j = 0; j < 4; ++j) {
        int m = tid + j * 256;
        if (m < Lp) {
            float v = e[j] * inv * mb[j];
            orow[m] = v;
            brow[m] = f2bf(v);
        } else if (m < KP) {
            brow[m] = 0;
        }
    }
}

// ---------------------------------------------------------------------------
// p62^T bf16: out[b][n][k] = x3[b, c(n), ih(k)*4+kh(n), iw(k)*4+kw(n)], ld KP.
// ---------------------------------------------------------------------------
__global__ __launch_bounds__(256)
void p62bt_k(const float* __restrict__ x3, unsigned short* __restrict__ out)
{
    int idx = blockIdx.x * 256 + threadIdx.x;      // 8*1568*124
    if (idx >= 8 * 1568 * 124) return;
    int ck = idx % 124;
    int t  = idx / 124;
    int n  = t % 1568;
    int b  = t / 1568;
    int c = n / 49, rr = n - c * 49;
    int kh = rr / 7, kw = rr - kh * 7;
    const float* src = x3 + (long long)b * 524288 + c * 16384 + kh * 128 + kw;
    int k = ck * 8;
    unsigned short v[8];
    #pragma unroll
    for (int j = 0; j < 8; ++j) {
        int kk = k + j;
        if (kk < Lp) {
            int ih = kk / 31, iw = kk - ih * 31;
            v[j] = f2bf(src[ih * 512 + iw * 4]);
        } else v[j] = 0;
    }
    *(short8x*)(out + ((long long)b * 1568 + n) * KP + k) = *(short8x*)v;
}

// ---------------------------------------------------------------------------
// y = Am @ p62 via bf16 MFMA, prefetched, writes yT bf16 [b][n][l] (ld YLD).
// r2 structure (measured best: 59 us): single LDS buffer, 2 barriers/K-step.
// NOTE buffer-placement sensitivity [r8/r9 lesson]: p62bT MUST be the Abuf
// region and yT the wfT region — the swapped placement measured 77 us twice
// (same code, same FETCH). Do not move these buffers.
// ---------------------------------------------------------------------------
__global__ __launch_bounds__(256)
void ymfma_k(const unsigned short* __restrict__ Amb,
             const unsigned short* __restrict__ Pbt,
             unsigned short* __restrict__ yT)
{
    __shared__ unsigned short As[128 * 32];
    __shared__ unsigned short Bs[128 * 32];
    const int b   = blockIdx.x & 7;
    const int t   = blockIdx.x >> 3;            // 104 = 13 n x 8 m
    const int tn0 = (t % 13) * 128;
    const int tm0 = (t / 13) * 128;
    const unsigned short* Ab = Amb + (long long)b * AMBB;
    const unsigned short* Bb = Pbt + (long long)b * PBTB;
    const int tid = threadIdx.x;

    const int sr  = tid >> 1;
    const int sc0 = (tid & 1) * 2;
    const bool aok = (tm0 + sr) < Lp;
    const bool bok = (tn0 + sr) < F62;
    const unsigned short* Arow = Ab + (long long)(tm0 + sr) * KP;
    const unsigned short* Brow = Bb + (long long)(tn0 + sr) * KP;
    const int swz = (sr >> 1) & 3;

    const int lane = tid & 63;
    const int wv   = tid >> 6;
    const int wm   = (wv >> 1) * 64, wn = (wv & 1) * 64;
    const int fr   = lane & 15;
    const int kq   = lane >> 4;

    floatx4 acc[4][4];
    #pragma unroll
    for (int i = 0; i < 4; ++i)
        #pragma unroll
        for (int j = 0; j < 4; ++j)
            acc[i][j] = (floatx4){0.f, 0.f, 0.f, 0.f};

    const short8x zz = {0,0,0,0,0,0,0,0};
    short8x pa[2], pb[2];
    auto loadK = [&](int k0) {
        #pragma unroll
        for (int c = 0; c < 2; ++c) {
            int kc = sc0 + c;
            pa[c] = aok ? *(const short8x*)(Arow + k0 + kc * 8) : zz;
            pb[c] = bok ? *(const short8x*)(Brow + k0 + kc * 8) : zz;
        }
    };

    loadK(0);
    for (int k0 = 0; k0 < Lp; k0 += 32) {
        #pragma unroll
        for (int c = 0; c < 2; ++c) {
            int pc = (sc0 + c) ^ swz;
            *(short8x*)&As[sr * 32 + pc * 8] = pa[c];
            *(short8x*)&Bs[sr * 32 + pc * 8] = pb[c];
        }
        __syncthreads();
        if (k0 + 32 < Lp) loadK(k0 + 32);
        short8x af[4], bfr[4];
        #pragma unroll
        for (int i = 0; i < 4; ++i) {
            int mr = wm + i * 16 + fr;
            af[i] = *(const short8x*)&As[mr * 32 + ((kq ^ ((mr >> 1) & 3)) * 8)];
        }
        #pragma unroll
        for (int j = 0; j < 4; ++j) {
            int nr = wn + j * 16 + fr;
            bfr[j] = *(const short8x*)&Bs[nr * 32 + ((kq ^ ((nr >> 1) & 3)) * 8)];
        }
        #pragma unroll
        for (int i = 0; i < 4; ++i)
            #pragma unroll
            for (int j = 0; j < 4; ++j)
                acc[i][j] = __builtin_amdgcn_mfma_f32_16x16x32_bf16(
                                af[i], bfr[j], acc[i][j], 0, 0, 0);
        __syncthreads();
    }

    unsigned short* Yb = yT + (long long)b * YB;
    #pragma unroll
    for (int j = 0; j < 4; ++j) {
        int n = tn0 + wn + j * 16 + fr;
        if (n >= F62) continue;
        unsigned short* Yr = Yb + (long long)n * YLD;
        #pragma unroll
        for (int i = 0; i < 4; ++i) {
            int lb = tm0 + wm + i * 16 + kq * 4;
            if (lb >= Lp) continue;
            ushort4x hv;
            #pragma unroll
            for (int r = 0; r < 4; ++r) hv[r] = f2bf(acc[i][j][r]);
            if (lb + 3 < Lp) {
                *(ushort4x*)(Yr + lb) = hv;
            } else {
                #pragma unroll
                for (int r = 0; r < 4; ++r)
                    if (lb + r < Lp) Yr[lb + r] = hv[r];
            }
        }
    }
}

// ---------------------------------------------------------------------------
// Launch
// ---------------------------------------------------------------------------
extern "C" void kernel_launch(void* const* d_in, const int* in_sizes, int n_in,
                              void* d_out, int out_size, void* d_ws, size_t ws_size,
                              hipStream_t stream)
{
    const float* x       = (const float*)d_in[0];
    const float* g_w     = (const float*)d_in[1];
    const float* g_b     = (const float*)d_in[2];
    const float* w_w     = (const float*)d_in[3];
    const float* w_b     = (const float*)d_in[4];
    const float* theta_w = (const float*)d_in[5];
    const float* theta_b = (const float*)d_in[6];
    const float* fc1_w   = (const float*)d_in[7];
    const float* fc1_b   = (const float*)d_in[8];
    const float* mconv_w = (const float*)d_in[9];
    const float* mconv_b = (const float*)d_in[10];
    const float* mfc_w   = (const float*)d_in[11];
    const float* mfc_b   = (const float*)d_in[12];
    const float* c1_w    = (const float*)d_in[13];
    const float* c2_w    = (const float*)d_in[14];

    float* Am_out    = (float*)d_out;
    float* final_out = Am_out + (size_t)Bn * Lp * Lp;

    // Workspace (floats), ~112 MB — r6 aliasing restored (ymfma placement-
    // sensitive: p62bT@Abuf / yT@wfT measured 59us; swapped = 77us).
    float* ws = (float*)d_ws;
    unsigned short* x1clH = (unsigned short*)ws;                // 2,097,152 shorts
    unsigned short* x1clL = (unsigned short*)(ws + 1048576);
    unsigned short* x2clH = (unsigned short*)(ws + 2097152);
    unsigned short* x2clL = (unsigned short*)(ws + 3145728);
    float* x1f   = ws;                        // final conv fp32 o1 (late reuse)
    float* x3    = ws + 4194304;              // 4,194,304 (theta conv1x1 out)
    unsigned short* xf_hi = (unsigned short*)(ws + 8388608);    // 1,722,112 shorts
    unsigned short* xf_lo = (unsigned short*)(ws + 9249664);
    unsigned short* wf_hi = (unsigned short*)(ws + 10110720);
    unsigned short* wf_lo = (unsigned short*)(ws + 10971776);
    float* Abuf  = ws + 11832832;             // 7,388,168 fl (xcl -> S -> p62bT -> fcl)
    unsigned short* wfT_hi = (unsigned short*)(ws + 19221000); // 1,555,456 shorts
    unsigned short* wfT_lo = (unsigned short*)(ws + 19998728);
    unsigned short* W2_hi  = (unsigned short*)(ws + 20776456); // 1,722,112 shorts
    unsigned short* W2_lo  = (unsigned short*)(ws + 21637512);
    unsigned short* Mw_hi = (unsigned short*)(ws + 26847496);  // 953,312 shorts
    unsigned short* Mw_lo = (unsigned short*)(ws + 27324152);
    float* Mb    = ws + 27800808;             // 1,024
    unsigned short* fc1wh = (unsigned short*)(ws + 27801832);  // 204,800 shorts
    unsigned short* fc1wl = (unsigned short*)(ws + 27904232);  // 204,800 shorts
    unsigned short* cwh = (unsigned short*)(ws + 4194304);     // 9,216 shorts
    unsigned short* cwl = cwh + 16384;
    unsigned short* c1h = (unsigned short*)(ws + 28006632);    // 4,608 shorts
    unsigned short* c1l = c1h + 8192;
    unsigned short* xclH = (unsigned short*)(ws + 11832832);   // 4,194,304 shorts
    unsigned short* xclL = (unsigned short*)(ws + 13929984);   // 4,194,304 shorts
    unsigned short* Am_bf16 = (unsigned short*)ws;   // x1/x2 slots (cl dead)
    unsigned short* p62bT   = (unsigned short*)Abuf; // aliases Abuf (S dead)
    unsigned short* yT      = wfT_hi;                // aliases wfT/W2 (dead)
    unsigned short* fclH    = xclH;                  // reused after ymfma
    unsigned short* fclL    = xclL;

    // merged prep
    prep_k<<<4778, 256, 0, stream>>>(
        g_w, w_w, c1_w, cwh, cwl, c1h, c1l,
        mconv_w, mfc_w, Mw_hi, Mw_lo,
        mconv_b, mfc_b, Mb, fc1_w, fc1wh, fc1wl,
        wfT_hi, wfT_lo);

    // x -> channel-last bf16 hi/lo
    cls_k<<<1024, 256, 0, stream>>>(x, xclH, xclL);

    // x1, x2 = dual 3x3 convs -> channel-last split outputs (CLOUT)
    convcl_k<32, true, false, true><<<1024, 256, 0, stream>>>(
        xclH, xclL, cwh, cwl, g_b, w_b,
        nullptr, x1clH, x1clL, x2clH, x2clL);

    // x3 = conv1x1(x1) from cl split
    conv1x1p_k<true, true, false, false><<<512, 256, 0, stream>>>(
        nullptr, x1clH, x1clL, theta_w, theta_b, nullptr, x3);

    // xf (from x1cl) + wf (from x2cl, + transposed) in ONE launch, vector A
    fcmfma2_k<<<968, 256, 0, stream>>>(
        x1clH, x1clL, x2clH, x2clL, fc1wh, fc1wl, fc1_b,
        xf_hi, xf_lo, wf_hi, wf_lo, wfT_hi, wfT_lo);

    // W2 = Mw @ wf (assoc. trick: Ti = (Mw@wf)@xf^T)
    w2mfma_k<<<128, 256, 0, stream>>>(
        Mw_hi, Mw_lo, wfT_hi, wfT_lo, W2_hi, W2_lo);

    // Fused: A = wf@xf^T, Ti = W2@xf^T + Mb, S = A*sigmoid(Ti)*scale
    atimfma_k<<<512, 256, 0, stream>>>(
        wf_hi, wf_lo, W2_hi, W2_lo, xf_hi, xf_lo, Mb, Abuf);

    // Am = softmax(S)*(S!=0) -> d_out fp32 + bf16
    softmax_mask_k<<<7688, 256, 0, stream>>>(Abuf, Am_out, Am_bf16);

    // p62^T bf16 (aliases Abuf; S dead)
    p62bt_k<<<6077, 256, 0, stream>>>(x3, p62bT);

    // y = Am @ p62 -> yT bf16 (wfT/W2 region dead), r2 structure
    ymfma_k<<<832, 256, 0, stream>>>(Am_bf16, p62bT, yT);

    // FUSED fold + channel-last split (p62bT dead; skips x3 round trip)
    foldcl_k<<<1024, 256, 0, stream>>>(yT, fclH, fclL);

    // o1 = leaky(conv3x3(refpad(fold))), fp32 out (Am_bf16 dead)
    convcl_k<16, false, true, false><<<1024, 256, 0, stream>>>(
        fclH, fclL, c1h, c1l, nullptr, nullptr,
        x1f, nullptr, nullptr, nullptr, nullptr);

    // final = x + leaky(conv1x1(o1))
    conv1x1p_k<false, false, true, true><<<512, 256, 0, stream>>>(
        x1f, nullptr, nullptr, c2_w, nullptr, x, final_out);
}